// Round 5
// baseline (74.321 us; speedup 1.0000x reference)
//
#include <hip/hip_runtime.h>

// 8-qubit VQC, CNOT chains folded into RX pairing masks (math validated R2-R4).
// R5 layout: 4 batch elements per wave64, one per 16-lane group.
// amp idx x = l4*16 + r (l4 = lane&15, r = reg 0..15):
//   x0<->lane bit3, x1<->lane bit2, x2<->lane bit1, x3<->lane bit0,
//   x4<->reg bit3,  x5<->reg bit2,  x6<->reg bit1,  x7<->reg bit0
// State = 32 VGPRs (re[16]+im[16]); weight trig inline per gate (2-reg live
// range). __launch_bounds__(256,8) targets <=64 VGPR -> 8 waves/SIMD.
// Cross-lane via DPP only: xor1/2/3 quad_perm, xor7 row_half_mirror,
// xor15 row_mirror; others composed.

template<int C>
__device__ __forceinline__ float dppf(float x) {
    const int xi = __float_as_int(x);
    return __int_as_float(__builtin_amdgcn_update_dpp(xi, xi, C, 0xF, 0xF, true));
}

// fetch value from lane ^ LM within each 16-lane group
template<int LM>
__device__ __forceinline__ float xfetch(float x) {
    if constexpr (LM == 1)       return dppf<0xB1>(x);
    else if constexpr (LM == 2)  return dppf<0x4E>(x);
    else if constexpr (LM == 3)  return dppf<0x1B>(x);
    else if constexpr (LM == 4)  return dppf<0x141>(dppf<0x1B>(x));
    else if constexpr (LM == 5)  return dppf<0x141>(dppf<0x4E>(x));
    else if constexpr (LM == 6)  return dppf<0x141>(dppf<0xB1>(x));
    else if constexpr (LM == 7)  return dppf<0x141>(x);
    else if constexpr (LM == 8)  return dppf<0x140>(dppf<0x141>(x));
    else if constexpr (LM == 10) return dppf<0x140>(dppf<0x141>(dppf<0x4E>(x)));
    else if constexpr (LM == 12) return dppf<0x140>(dppf<0x1B>(x));
    else                         return dppf<0x140>(x);   // LM == 15
}

// ds_swizzle broadcast of lane j within each 8-lane group (16 uses total)
template<int OFF>
__device__ __forceinline__ float swz(float x) {
    return __int_as_float(__builtin_amdgcn_ds_swizzle(__float_as_int(x), OFF));
}

constexpr int hibit(int m) { return m >= 8 ? 8 : m >= 4 ? 4 : m >= 2 ? 2 : 1; }

// RX-type mixing along (LM lane-bits, RM reg-bits): new = c*a - i*s*partner
template<int LM, int RM>
__device__ __forceinline__ void gate(float re[16], float im[16], float cg, float sg) {
    if constexpr (RM == 0) {
#pragma unroll
        for (int r = 0; r < 16; ++r) {
            const float pr = xfetch<LM>(re[r]);
            const float pi = xfetch<LM>(im[r]);
            const float nr = cg * re[r] + sg * pi;
            const float ni = cg * im[r] - sg * pr;
            re[r] = nr; im[r] = ni;
        }
    } else {
        constexpr int HB = hibit(RM);
#pragma unroll
        for (int a = 0; a < 16; ++a) {
            if (a & HB) continue;                // closed pair {a, b}, a < b
            const int b = a ^ RM;
            float pra, pia, prb, pib;
            if constexpr (LM != 0) {
                prb = xfetch<LM>(re[b]); pib = xfetch<LM>(im[b]);
                pra = xfetch<LM>(re[a]); pia = xfetch<LM>(im[a]);
            } else {
                prb = re[b]; pib = im[b]; pra = re[a]; pia = im[a];
            }
            const float nra = cg * re[a] + sg * pib;
            const float nia = cg * im[a] - sg * prb;
            const float nrb = cg * re[b] + sg * pia;
            const float nib = cg * im[b] - sg * pra;
            re[a] = nra; im[a] = nia; re[b] = nrb; im[b] = nib;
        }
    }
}

__global__ __launch_bounds__(256, 8) void vqc_kernel(
    const float* __restrict__ inputs,   // (B, 8)
    const float* __restrict__ weights,  // (2, 8)
    float* __restrict__ out)            // (B, 8)
{
    const int tid = threadIdx.x;
    const int l4 = tid & 15;
    const int e = (blockIdx.x << 4) + (tid >> 4);     // one element per 16-lane group

    // ---- per-element trig: lanes j and j+8 of each group compute angle j ----
    const float ang = inputs[(e << 3) + (l4 & 7)];
    const float ch = __cosf(0.5f * ang);
    const float sh = __sinf(0.5f * ang);

    // broadcast (c_j, s_j) within each 8-half (both halves hold identical data)
    float bc[8], bs[8];
    bc[0] = swz<(0 << 5) | 0x18>(ch); bs[0] = swz<(0 << 5) | 0x18>(sh);
    bc[1] = swz<(1 << 5) | 0x18>(ch); bs[1] = swz<(1 << 5) | 0x18>(sh);
    bc[2] = swz<(2 << 5) | 0x18>(ch); bs[2] = swz<(2 << 5) | 0x18>(sh);
    bc[3] = swz<(3 << 5) | 0x18>(ch); bs[3] = swz<(3 << 5) | 0x18>(sh);
    bc[4] = swz<(4 << 5) | 0x18>(ch); bs[4] = swz<(4 << 5) | 0x18>(sh);
    bc[5] = swz<(5 << 5) | 0x18>(ch); bs[5] = swz<(5 << 5) | 0x18>(sh);
    bc[6] = swz<(6 << 5) | 0x18>(ch); bs[6] = swz<(6 << 5) | 0x18>(sh);
    bc[7] = swz<(7 << 5) | 0x18>(ch); bs[7] = swz<(7 << 5) | 0x18>(sh);

    // ---- initial product state RY(x)|0..0> (all real) ----
    const float v0 = (l4 & 8) ? bs[0] : bc[0];
    const float v1 = (l4 & 4) ? bs[1] : bc[1];
    const float v2 = (l4 & 2) ? bs[2] : bc[2];
    const float v3 = (l4 & 1) ? bs[3] : bc[3];
    const float lp = (v0 * v1) * (v2 * v3);

    float t4[4], t8[8];
    t4[0] = bc[6] * bc[7]; t4[1] = bc[6] * bs[7];
    t4[2] = bs[6] * bc[7]; t4[3] = bs[6] * bs[7];
#pragma unroll
    for (int k = 0; k < 4; ++k) { t8[k] = bc[5] * t4[k]; t8[4 + k] = bs[5] * t4[k]; }
    const float lc = lp * bc[4], ls = lp * bs[4];
    float re[16], im[16];
#pragma unroll
    for (int k = 0; k < 8; ++k) { re[k] = lc * t8[k]; re[8 + k] = ls * t8[k]; }
#pragma unroll
    for (int r = 0; r < 16; ++r) im[r] = 0.0f;

    // ---- gates; weight trig inline (wave-uniform, 2-reg live range) ----
#define GATE(LM, RM, IDX)                                                   \
    { const float x_ = 0.5f * weights[IDX];                                 \
      gate<LM, RM>(re, im, __cosf(x_), __sinf(x_)); }

    // layer 1 (masks e_q ^ e_{q+1}); q0 specialized for im == 0
    {
        const float x_ = 0.5f * weights[0];
        const float cg = __cosf(x_), sg = __sinf(x_);
#pragma unroll
        for (int r = 0; r < 16; ++r) {
            const float pr = xfetch<12>(re[r]);
            im[r] = -sg * pr;
            re[r] = cg * re[r];
        }
    }
    GATE( 6,  0, 1)   // q1: lanes {x1,x2}
    GATE( 3,  0, 2)   // q2
    GATE( 1,  8, 3)   // q3: lane bit0 + reg bit3
    GATE( 0, 12, 4)   // q4: regs {3,2}
    GATE( 0,  6, 5)   // q5
    GATE( 0,  3, 6)   // q6
    GATE( 0,  1, 7)   // q7

    // layer 2 (masks e_q ^ e_{q+2}, e_8+ = 0)
    GATE(10,  0,  8)  // q0: lanes {x0,x2}
    GATE( 5,  0,  9)  // q1
    GATE( 2,  8, 10)  // q2: lane bit1 + reg bit3
    GATE( 1,  4, 11)  // q3: lane bit0 + reg bit2
    GATE( 0, 10, 12)  // q4
    GATE( 0,  5, 13)  // q5
    GATE( 0,  2, 14)  // q6
    GATE( 0,  1, 15)  // q7
#undef GATE

    // ---- measurement ----
    float p[16];
#pragma unroll
    for (int r = 0; r < 16; ++r) p[r] = re[r] * re[r] + im[r] * im[r];

    // reg-side signed folds (reg bit3=x4, bit2=x5, bit1=x6, bit0=x7):
    // A: none  B:{b3}  C:{b2}  D:{b3,b1}  E:{b2,b0}
    float u[8], v[8];
#pragma unroll
    for (int k = 0; k < 8; ++k) { u[k] = p[2 * k] + p[2 * k + 1]; v[k] = p[2 * k] - p[2 * k + 1]; }
    float uu[4], ud[4], vu[4];
#pragma unroll
    for (int k = 0; k < 4; ++k) {
        uu[k] = u[2 * k] + u[2 * k + 1];
        ud[k] = u[2 * k] - u[2 * k + 1];
        vu[k] = v[2 * k] + v[2 * k + 1];
    }
    float uuu[2], uud[2], udu[2], vud[2];
#pragma unroll
    for (int k = 0; k < 2; ++k) {
        uuu[k] = uu[2 * k] + uu[2 * k + 1];
        uud[k] = uu[2 * k] - uu[2 * k + 1];
        udu[k] = ud[2 * k] + ud[2 * k + 1];
        vud[k] = vu[2 * k] - vu[2 * k + 1];
    }
    float A = uuu[0] + uuu[1];   // no reg signs  (q0..q3)
    float B = uuu[0] - uuu[1];   // {x4}          (q4)
    float C = uud[0] + uud[1];   // {x5}          (q5)
    float D = udu[0] - udu[1];   // {x4,x6}       (q6)
    float E = vud[0] + vud[1];   // {x5,x7}       (q7)

    // ---- 4-stage lane WHT within each 16-group (DPP) ----
    const float sg0 = (l4 & 1) ? -1.0f : 1.0f;
    const float sg1 = (l4 & 2) ? -1.0f : 1.0f;
    const float sg2 = (l4 & 4) ? -1.0f : 1.0f;
    const float sg3 = (l4 & 8) ? -1.0f : 1.0f;
#define WSTAGE(x, M, sgn) { const float b_ = xfetch<M>(x); x = __builtin_fmaf(sgn, x, b_); }
#define WHT4(x) WSTAGE(x, 1, sg0) WSTAGE(x, 2, sg1) WSTAGE(x, 4, sg2) WSTAGE(x, 8, sg3)
    WHT4(A) WHT4(B) WHT4(C) WHT4(D) WHT4(E)
#undef WHT4
#undef WSTAGE

    // lane-sign masks: q0:{x0}=8  q1:{x1}=4  q2:{x0,x2}=10  q3:{x1,x3}=5
    //                  q4:B@10  q5:C@5  q6:D@10  q7:E@5
    float* o = out + (size_t)e * 8;
    if (l4 == 8) {
        o[0] = A;
    } else if (l4 == 4) {
        o[1] = A;
    } else if (l4 == 10) {
        o[2] = A; o[4] = B; o[6] = D;
    } else if (l4 == 5) {
        o[3] = A; o[5] = C; o[7] = E;
    }
}

extern "C" void kernel_launch(void* const* d_in, const int* in_sizes, int n_in,
                              void* d_out, int out_size, void* d_ws, size_t ws_size,
                              hipStream_t stream) {
    const float* inputs  = (const float*)d_in[0];
    const float* weights = (const float*)d_in[1];
    float* out = (float*)d_out;
    const int B = in_sizes[0] / 8;          // 32768
    hipLaunchKernelGGL(vqc_kernel, dim3(B / 16), dim3(256), 0, stream,
                       inputs, weights, out);
}

// Round 6
// 67.988 us; speedup vs baseline: 1.0931x; 1.0931x over previous
//
#include <hip/hip_runtime.h>

// 8-qubit VQC, CNOT chains folded into RX pairing masks (math validated R2-R5).
// R6: back to R4's layout (8 elements/wave64, one per 8-lane group, 32 complex
// amps per lane), but state held as float2 (re,im) and gate math done with
// packed-FP32 (v_pk_fma_f32 / v_pk_mul_f32 via ext_vector float2 arithmetic):
//   new = c2*a + sn*swap(partner),  c2=(c,c), sn=(s,-s), swap=(y,x) op_sel.
// This halves gate-math VALU instructions (2 pk ops per amp per gate vs 4).
// amp idx x = l3*32 + r: x0<->lane bit2, x1<->lane bit1, x2<->lane bit0,
//   x3..x7 <-> reg bits 4..0. Cross-lane via DPP (quad_perm / row_half_mirror).

typedef float v2f __attribute__((ext_vector_type(2)));

template<int C>
__device__ __forceinline__ float dppf(float x) {
    const int xi = __float_as_int(x);
    return __int_as_float(__builtin_amdgcn_update_dpp(xi, xi, C, 0xF, 0xF, true));
}

// fetch value from lane ^ LM (LM in 1..7, within each 8-lane group)
template<int LM>
__device__ __forceinline__ float xfetch(float x) {
    if constexpr (LM == 1)      return dppf<0xB1>(x);
    else if constexpr (LM == 2) return dppf<0x4E>(x);
    else if constexpr (LM == 3) return dppf<0x1B>(x);
    else if constexpr (LM == 4) return dppf<0x141>(dppf<0x1B>(x));
    else if constexpr (LM == 5) return dppf<0x141>(dppf<0x4E>(x));
    else if constexpr (LM == 6) return dppf<0x141>(dppf<0xB1>(x));
    else                        return dppf<0x141>(x);   // LM == 7
}

template<int LM>
__device__ __forceinline__ v2f xfetch2(v2f a) {
    v2f p;
    p.x = xfetch<LM>(a.x);
    p.y = xfetch<LM>(a.y);
    return p;
}

__device__ __forceinline__ v2f swapv(v2f p) {
    return __builtin_shufflevector(p, p, 1, 0);
}

// ds_swizzle broadcast of lane j within each 8-lane group
template<int OFF>
__device__ __forceinline__ float swz(float x) {
    return __int_as_float(__builtin_amdgcn_ds_swizzle(__float_as_int(x), OFF));
}

constexpr int hibit(int m) { return m >= 16 ? 16 : m >= 8 ? 8 : m >= 4 ? 4 : m >= 2 ? 2 : 1; }

// RX-type mixing along (LM lane-bits, RM reg-bits): new = c*a - i*s*partner
// packed: new = c2*a + sn*swap(p), sn = (s, -s)
template<int LM, int RM>
__device__ __forceinline__ void gate(v2f amp[32], float cg, float sg) {
    const v2f c2 = {cg, cg};
    const v2f sn = {sg, -sg};
    if constexpr (RM == 0) {
#pragma unroll
        for (int r = 0; r < 32; ++r) {
            const v2f p = xfetch2<LM>(amp[r]);
            amp[r] = c2 * amp[r] + sn * swapv(p);
        }
    } else {
        constexpr int HB = hibit(RM);
#pragma unroll
        for (int a = 0; a < 32; ++a) {
            if (a & HB) continue;                // closed pair {a, b}, a < b
            const int b = a ^ RM;
            v2f pa, pb;
            if constexpr (LM != 0) {
                pb = xfetch2<LM>(amp[b]);
                pa = xfetch2<LM>(amp[a]);
            } else {
                pb = amp[b];
                pa = amp[a];
            }
            const v2f na = c2 * amp[a] + sn * swapv(pb);
            const v2f nb = c2 * amp[b] + sn * swapv(pa);
            amp[a] = na;
            amp[b] = nb;
        }
    }
}

__global__ __launch_bounds__(256, 4) void vqc_kernel(
    const float* __restrict__ inputs,   // (B, 8)
    const float* __restrict__ weights,  // (2, 8)
    float* __restrict__ out)            // (B, 8)
{
    const int tid = threadIdx.x;
    const int l3 = tid & 7;
    const int e = (blockIdx.x << 5) + (tid >> 3);     // this group's batch element

    // ---- per-element trig, lane-parallel: lane j of each group does angle j ----
    const float ang = inputs[(blockIdx.x << 8) + tid];  // coalesced
    const float ch = __cosf(0.5f * ang);
    const float sh = __sinf(0.5f * ang);

    // broadcast (c_j, s_j) to all 8 lanes of the group (ds_swizzle bcast)
    float bc[8], bs[8];
    bc[0] = swz<(0 << 5) | 0x18>(ch); bs[0] = swz<(0 << 5) | 0x18>(sh);
    bc[1] = swz<(1 << 5) | 0x18>(ch); bs[1] = swz<(1 << 5) | 0x18>(sh);
    bc[2] = swz<(2 << 5) | 0x18>(ch); bs[2] = swz<(2 << 5) | 0x18>(sh);
    bc[3] = swz<(3 << 5) | 0x18>(ch); bs[3] = swz<(3 << 5) | 0x18>(sh);
    bc[4] = swz<(4 << 5) | 0x18>(ch); bs[4] = swz<(4 << 5) | 0x18>(sh);
    bc[5] = swz<(5 << 5) | 0x18>(ch); bs[5] = swz<(5 << 5) | 0x18>(sh);
    bc[6] = swz<(6 << 5) | 0x18>(ch); bs[6] = swz<(6 << 5) | 0x18>(sh);
    bc[7] = swz<(7 << 5) | 0x18>(ch); bs[7] = swz<(7 << 5) | 0x18>(sh);

    // ---- initial product state RY(x)|0..0> (all real) ----
    const float v0 = (l3 & 4) ? bs[0] : bc[0];
    const float v1 = (l3 & 2) ? bs[1] : bc[1];
    const float v2 = (l3 & 1) ? bs[2] : bc[2];
    const float lp = v0 * v1 * v2;

    float t4[4], t8[8], t16[16], re[32];
    t4[0] = bc[6] * bc[7]; t4[1] = bc[6] * bs[7];
    t4[2] = bs[6] * bc[7]; t4[3] = bs[6] * bs[7];
#pragma unroll
    for (int k = 0; k < 4; ++k) { t8[k] = bc[5] * t4[k]; t8[4 + k] = bs[5] * t4[k]; }
#pragma unroll
    for (int k = 0; k < 8; ++k) { t16[k] = bc[4] * t8[k]; t16[8 + k] = bs[4] * t8[k]; }
    const float lpc = lp * bc[3], lps = lp * bs[3];
#pragma unroll
    for (int k = 0; k < 16; ++k) { re[k] = lpc * t16[k]; re[16 + k] = lps * t16[k]; }

    // ---- layer 1, q0 (LM=6) specialized for im == 0; builds packed state ----
    v2f amp[32];
    {
        const float x_ = 0.5f * weights[0];
        const float cg = __cosf(x_), sg = __sinf(x_);
#pragma unroll
        for (int r = 0; r < 32; ++r) {
            const float pr = xfetch<6>(re[r]);
            amp[r].x = cg * re[r];
            amp[r].y = -sg * pr;
        }
    }

#define GATE(LM, RM, IDX)                                                   \
    { const float x_ = 0.5f * weights[IDX];                                 \
      gate<LM, RM>(amp, __cosf(x_), __sinf(x_)); }

    // layer 1 (masks e_q ^ e_{q+1})
    GATE( 3,  0, 1)   // q1: lanes {1,0}
    GATE( 1, 16, 2)   // q2: lane0 + reg bit4
    GATE( 0, 24, 3)   // q3: regs {4,3}
    GATE( 0, 12, 4)   // q4
    GATE( 0,  6, 5)   // q5
    GATE( 0,  3, 6)   // q6
    GATE( 0,  1, 7)   // q7

    // layer 2 (masks e_q ^ e_{q+2}, e_8+ = 0)
    GATE( 5,  0,  8)  // q0: lanes {2,0}
    GATE( 2, 16,  9)  // q1: lane1 + reg bit4
    GATE( 1,  8, 10)  // q2: lane0 + reg bit3
    GATE( 0, 20, 11)  // q3: regs {4,2}
    GATE( 0, 10, 12)  // q4
    GATE( 0,  5, 13)  // q5
    GATE( 0,  2, 14)  // q6
    GATE( 0,  1, 15)  // q7
#undef GATE

    // ---- measurement ----
    float p[32];
#pragma unroll
    for (int r = 0; r < 32; ++r) {
        const v2f q = amp[r] * amp[r];   // v_pk_mul_f32
        p[r] = q.x + q.y;
    }

    // reg-side signed folds. Sign sets on reg bits (bit4=x3..bit0=x7):
    // A:none  P1:{4}  P2:{3}  P3:{4,2}  P4:{3,1}  P5:{4,2,0}
    float u[16], v[16];
#pragma unroll
    for (int k = 0; k < 16; ++k) { u[k] = p[2 * k] + p[2 * k + 1]; v[k] = p[2 * k] - p[2 * k + 1]; }
    float uu[8], ud[8], vu[8];
#pragma unroll
    for (int k = 0; k < 8; ++k) {
        uu[k] = u[2 * k] + u[2 * k + 1];
        ud[k] = u[2 * k] - u[2 * k + 1];
        vu[k] = v[2 * k] + v[2 * k + 1];
    }
    float uuu[4], uud[4], udu[4], vud[4];
#pragma unroll
    for (int k = 0; k < 4; ++k) {
        uuu[k] = uu[2 * k] + uu[2 * k + 1];
        uud[k] = uu[2 * k] - uu[2 * k + 1];
        udu[k] = ud[2 * k] + ud[2 * k + 1];
        vud[k] = vu[2 * k] - vu[2 * k + 1];
    }
    float a2[2], b2[2], c2[2], d2[2], e2[2];
#pragma unroll
    for (int k = 0; k < 2; ++k) {
        a2[k] = uuu[2 * k] + uuu[2 * k + 1];
        b2[k] = uuu[2 * k] - uuu[2 * k + 1];
        c2[k] = uud[2 * k] + uud[2 * k + 1];
        d2[k] = udu[2 * k] - udu[2 * k + 1];
        e2[k] = vud[2 * k] + vud[2 * k + 1];
    }
    float SA = a2[0] + a2[1];   // lane masks: q0@4, q1@2, q2@5
    float S1 = a2[0] - a2[1];   // q3 @ lane-mask 2
    float S2 = b2[0] + b2[1];   // q4 @ 5
    float S3 = c2[0] - c2[1];   // q5 @ 2
    float S4 = d2[0] + d2[1];   // q6 @ 5
    float S5 = e2[0] - e2[1];   // q7 @ 2

    // ---- 3-stage lane WHT within each 8-group (DPP) ----
    const float sg0 = (l3 & 1) ? -1.0f : 1.0f;
    const float sg1 = (l3 & 2) ? -1.0f : 1.0f;
    const float sg2 = (l3 & 4) ? -1.0f : 1.0f;
#define WSTAGE(x, M, sgn) { const float b_ = xfetch<M>(x); x = __builtin_fmaf(sgn, x, b_); }
#define WHT3(x) WSTAGE(x, 1, sg0) WSTAGE(x, 2, sg1) WSTAGE(x, 4, sg2)
    WHT3(SA) WHT3(S1) WHT3(S2) WHT3(S3) WHT3(S4) WHT3(S5)
#undef WHT3
#undef WSTAGE

    float* o = out + (size_t)e * 8;
    if (l3 == 4) {
        o[0] = SA;
    } else if (l3 == 2) {
        o[1] = SA; o[3] = S1; o[5] = S3; o[7] = S5;
    } else if (l3 == 5) {
        o[2] = SA; o[4] = S2; o[6] = S4;
    }
}

extern "C" void kernel_launch(void* const* d_in, const int* in_sizes, int n_in,
                              void* d_out, int out_size, void* d_ws, size_t ws_size,
                              hipStream_t stream) {
    const float* inputs  = (const float*)d_in[0];
    const float* weights = (const float*)d_in[1];
    float* out = (float*)d_out;
    const int B = in_sizes[0] / 8;          // 32768
    hipLaunchKernelGGL(vqc_kernel, dim3(B / 32), dim3(256), 0, stream,
                       inputs, weights, out);
}